// Round 2
// baseline (433.501 us; speedup 1.0000x reference)
//
#include <hip/hip_runtime.h>

#define H 4096
#define THREADS 256
#define ROWS 2
#define CHUNKS 4   // H / (THREADS * 4)

__device__ __forceinline__ float dot4(float4 a, float4 b) {
    return a.x * b.x + a.y * b.y + a.z * b.z + a.w * b.w;
}

// Tiny pre-kernel: C[r'][r] = sum_d A_v[r'][d] * B_q[d][r]   (4x4)
__global__ void __launch_bounds__(THREADS) compute_C_kernel(
    const float* __restrict__ A_v, const float* __restrict__ B_q,
    float* __restrict__ C)
{
    const int tid = threadIdx.x;
    float acc[4][4];
#pragma unroll
    for (int i = 0; i < 4; ++i)
#pragma unroll
        for (int j = 0; j < 4; ++j) acc[i][j] = 0.f;

#pragma unroll
    for (int c = 0; c < CHUNKS; ++c) {
        const int d0 = c * (THREADS * 4) + tid * 4;
        float avf[4][4], bqf[4][4];
#pragma unroll
        for (int r = 0; r < 4; ++r) {
            float4 t = *reinterpret_cast<const float4*>(A_v + (size_t)r * H + d0);
            avf[r][0] = t.x; avf[r][1] = t.y; avf[r][2] = t.z; avf[r][3] = t.w;
        }
#pragma unroll
        for (int i = 0; i < 4; ++i) {
            float4 t = *reinterpret_cast<const float4*>(B_q + (size_t)(d0 + i) * 4);
            bqf[i][0] = t.x; bqf[i][1] = t.y; bqf[i][2] = t.z; bqf[i][3] = t.w;
        }
#pragma unroll
        for (int i = 0; i < 4; ++i)
#pragma unroll
            for (int rp = 0; rp < 4; ++rp)
#pragma unroll
                for (int r = 0; r < 4; ++r)
                    acc[rp][r] += avf[rp][i] * bqf[i][r];
    }

    const int lane = tid & 63, wave = tid >> 6;
    __shared__ float red[4][16];
#pragma unroll
    for (int rp = 0; rp < 4; ++rp)
#pragma unroll
        for (int r = 0; r < 4; ++r) {
            float v = acc[rp][r];
#pragma unroll
            for (int off = 32; off; off >>= 1) v += __shfl_down(v, off, 64);
            if (lane == 0) red[wave][rp * 4 + r] = v;
        }
    __syncthreads();
    if (tid < 16) C[tid] = red[0][tid] + red[1][tid] + red[2][tid] + red[3][tid];
}

// Fused kernel, VGPR-lean (target <=64 for 8 waves/SIMD).
// Phase 1: per-row rank-4 reductions (x read once, discarded).
// Phase 2: out = 2*(x + lq.Bq[d] + lv.Bv[d])  (x re-read; L1/L2-hot).
__global__ void __launch_bounds__(THREADS, 8) lora_fused_kernel(
    const float* __restrict__ x,
    const float* __restrict__ A_q, const float* __restrict__ B_q,
    const float* __restrict__ A_v, const float* __restrict__ B_v,
    const float* __restrict__ C,
    float* __restrict__ out)
{
    const int tid = threadIdx.x;
    const size_t row0 = (size_t)blockIdx.x * ROWS;
    const float* xbase = x + row0 * H;

    float accq[ROWS][4], accv[ROWS][4];
#pragma unroll
    for (int m = 0; m < ROWS; ++m)
#pragma unroll
        for (int r = 0; r < 4; ++r) { accq[m][r] = 0.f; accv[m][r] = 0.f; }

    // ---- Phase 1: rank-4 projections ----
#pragma unroll
    for (int c = 0; c < CHUNKS; ++c) {
        const int d0 = c * (THREADS * 4) + tid * 4;
        float4 xv[ROWS];
#pragma unroll
        for (int m = 0; m < ROWS; ++m)
            xv[m] = *reinterpret_cast<const float4*>(xbase + (size_t)m * H + d0);
#pragma unroll
        for (int r = 0; r < 4; ++r) {
            float4 aq = *reinterpret_cast<const float4*>(A_q + (size_t)r * H + d0);
#pragma unroll
            for (int m = 0; m < ROWS; ++m) accq[m][r] += dot4(xv[m], aq);
        }
#pragma unroll
        for (int r = 0; r < 4; ++r) {
            float4 av = *reinterpret_cast<const float4*>(A_v + (size_t)r * H + d0);
#pragma unroll
            for (int m = 0; m < ROWS; ++m) accv[m][r] += dot4(xv[m], av);
        }
    }

    // ---- Block reduction: 16 values (lq[2][4], lvx[2][4]) ----
    const int lane = tid & 63, wave = tid >> 6;
    __shared__ float red[4][16];
    __shared__ float lows[16];
#pragma unroll
    for (int i = 0; i < 16; ++i) {
        const int m = (i >> 2) & 1, r = i & 3;
        float v = (i < 8) ? accq[m][r] : accv[m][r];
#pragma unroll
        for (int off = 1; off < 64; off <<= 1) v += __shfl_xor(v, off, 64);
        if (lane == 0) red[wave][i] = v;
    }
    __syncthreads();
    if (tid < 16) lows[tid] = red[0][tid] + red[1][tid] + red[2][tid] + red[3][tid];
    __syncthreads();

    // Every thread reads the 16 lows + C, forms lq/lv locally (L1 broadcast).
    float lq[ROWS][4], lv[ROWS][4];
    {
        float cm[16];
#pragma unroll
        for (int i = 0; i < 16; ++i) cm[i] = C[i];
#pragma unroll
        for (int m = 0; m < ROWS; ++m) {
#pragma unroll
            for (int r = 0; r < 4; ++r) lq[m][r] = lows[m * 4 + r];
#pragma unroll
            for (int rp = 0; rp < 4; ++rp) {
                float s = lows[8 + m * 4 + rp];
#pragma unroll
                for (int r = 0; r < 4; ++r) s += 2.f * lq[m][r] * cm[rp * 4 + r];
                lv[m][rp] = s;
            }
        }
    }

    // ---- Phase 2: apply ----
#pragma unroll
    for (int c = 0; c < CHUNKS; ++c) {
        const int d0 = c * (THREADS * 4) + tid * 4;
        float4 xv[ROWS];
        float o[ROWS][4];
#pragma unroll
        for (int m = 0; m < ROWS; ++m)
            xv[m] = *reinterpret_cast<const float4*>(xbase + (size_t)m * H + d0);
#pragma unroll
        for (int i = 0; i < 4; ++i) {
            float4 bq = *reinterpret_cast<const float4*>(B_q + (size_t)(d0 + i) * 4);
            float4 bv = *reinterpret_cast<const float4*>(B_v + (size_t)(d0 + i) * 4);
#pragma unroll
            for (int m = 0; m < ROWS; ++m) {
                float xs = (i == 0) ? xv[m].x : (i == 1) ? xv[m].y : (i == 2) ? xv[m].z : xv[m].w;
                float dq = lq[m][0] * bq.x + lq[m][1] * bq.y + lq[m][2] * bq.z + lq[m][3] * bq.w;
                float dv = lv[m][0] * bv.x + lv[m][1] * bv.y + lv[m][2] * bv.z + lv[m][3] * bv.w;
                o[m][i] = 2.f * (xs + dq + dv);
            }
        }
#pragma unroll
        for (int m = 0; m < ROWS; ++m) {
            float4 ov = make_float4(o[m][0], o[m][1], o[m][2], o[m][3]);
            *reinterpret_cast<float4*>(out + (row0 + m) * H + d0) = ov;
        }
    }
}

extern "C" void kernel_launch(void* const* d_in, const int* in_sizes, int n_in,
                              void* d_out, int out_size, void* d_ws, size_t ws_size,
                              hipStream_t stream) {
    const float* x   = (const float*)d_in[0];
    const float* A_q = (const float*)d_in[1];
    const float* B_q = (const float*)d_in[2];
    const float* A_v = (const float*)d_in[3];
    const float* B_v = (const float*)d_in[4];
    float* out = (float*)d_out;
    float* C   = (float*)d_ws;          // 16 floats

    const int rows = in_sizes[0] / H;   // B*S = 8192

    compute_C_kernel<<<1, THREADS, 0, stream>>>(A_v, B_q, C);
    lora_fused_kernel<<<rows / ROWS, THREADS, 0, stream>>>(
        x, A_q, B_q, A_v, B_v, C, out);
}

// Round 3
// 330.751 us; speedup vs baseline: 1.3107x; 1.3107x over previous
//
#include <hip/hip_runtime.h>

#define H 4096
#define THREADS 256
#define ROWS 2
#define CHUNKS 4   // H / (THREADS * 4)

__device__ __forceinline__ float dot4(float4 a, float4 b) {
    return a.x * b.x + a.y * b.y + a.z * b.z + a.w * b.w;
}

// Tiny pre-kernel: C[r'][r] = sum_d A_v[r'][d] * B_q[d][r]   (4x4)
__global__ void __launch_bounds__(THREADS) compute_C_kernel(
    const float* __restrict__ A_v, const float* __restrict__ B_q,
    float* __restrict__ C)
{
    const int tid = threadIdx.x;
    float acc[4][4];
#pragma unroll
    for (int i = 0; i < 4; ++i)
#pragma unroll
        for (int j = 0; j < 4; ++j) acc[i][j] = 0.f;

#pragma unroll
    for (int c = 0; c < CHUNKS; ++c) {
        const int d0 = c * (THREADS * 4) + tid * 4;
        float avf[4][4], bqf[4][4];
#pragma unroll
        for (int r = 0; r < 4; ++r) {
            float4 t = *reinterpret_cast<const float4*>(A_v + (size_t)r * H + d0);
            avf[r][0] = t.x; avf[r][1] = t.y; avf[r][2] = t.z; avf[r][3] = t.w;
        }
#pragma unroll
        for (int i = 0; i < 4; ++i) {
            float4 t = *reinterpret_cast<const float4*>(B_q + (size_t)(d0 + i) * 4);
            bqf[i][0] = t.x; bqf[i][1] = t.y; bqf[i][2] = t.z; bqf[i][3] = t.w;
        }
#pragma unroll
        for (int i = 0; i < 4; ++i)
#pragma unroll
            for (int rp = 0; rp < 4; ++rp)
#pragma unroll
                for (int r = 0; r < 4; ++r)
                    acc[rp][r] += avf[rp][i] * bqf[i][r];
    }

    const int lane = tid & 63, wave = tid >> 6;
    __shared__ float red[4][16];
#pragma unroll
    for (int rp = 0; rp < 4; ++rp)
#pragma unroll
        for (int r = 0; r < 4; ++r) {
            float v = acc[rp][r];
#pragma unroll
            for (int off = 32; off; off >>= 1) v += __shfl_down(v, off, 64);
            if (lane == 0) red[wave][rp * 4 + r] = v;
        }
    __syncthreads();
    if (tid < 16) C[tid] = red[0][tid] + red[1][tid] + red[2][tid] + red[3][tid];
}

// Fused kernel: x read ONCE (kept in registers across the block reduction),
// out written once. ROWS=2 keeps x staging at 32 VGPRs so we land in a
// higher occupancy tier than R0's ROWS=4 (104 VGPR -> 4 waves/SIMD).
__global__ void __launch_bounds__(THREADS, 6) lora_fused_kernel(
    const float* __restrict__ x,
    const float* __restrict__ A_q, const float* __restrict__ B_q,
    const float* __restrict__ A_v, const float* __restrict__ B_v,
    const float* __restrict__ C,
    float* __restrict__ out)
{
    const int tid = threadIdx.x;
    const size_t row0 = (size_t)blockIdx.x * ROWS;
    const float* xbase = x + row0 * H;

    float4 xr[ROWS][CHUNKS];            // 32 VGPRs: x stays in registers
    float accq[ROWS][4], accv[ROWS][4];
#pragma unroll
    for (int m = 0; m < ROWS; ++m)
#pragma unroll
        for (int r = 0; r < 4; ++r) { accq[m][r] = 0.f; accv[m][r] = 0.f; }

    // ---- Phase 1: rank-4 projections (x loaded once, kept) ----
#pragma unroll
    for (int c = 0; c < CHUNKS; ++c) {
        const int d0 = c * (THREADS * 4) + tid * 4;
#pragma unroll
        for (int m = 0; m < ROWS; ++m)
            xr[m][c] = *reinterpret_cast<const float4*>(xbase + (size_t)m * H + d0);
#pragma unroll
        for (int r = 0; r < 4; ++r) {
            float4 aq = *reinterpret_cast<const float4*>(A_q + (size_t)r * H + d0);
#pragma unroll
            for (int m = 0; m < ROWS; ++m) accq[m][r] += dot4(xr[m][c], aq);
        }
#pragma unroll
        for (int r = 0; r < 4; ++r) {
            float4 av = *reinterpret_cast<const float4*>(A_v + (size_t)r * H + d0);
#pragma unroll
            for (int m = 0; m < ROWS; ++m) accv[m][r] += dot4(xr[m][c], av);
        }
    }

    // ---- Block reduction: 16 values (lq[2][4], lvx[2][4]) ----
    const int lane = tid & 63, wave = tid >> 6;
    __shared__ float red[4][16];
    __shared__ float lows[16];
#pragma unroll
    for (int i = 0; i < 16; ++i) {
        const int m = (i >> 2) & 1, r = i & 3;
        float v = (i < 8) ? accq[m][r] : accv[m][r];
#pragma unroll
        for (int off = 1; off < 64; off <<= 1) v += __shfl_xor(v, off, 64);
        if (lane == 0) red[wave][i] = v;
    }
    __syncthreads();
    if (tid < 16) lows[tid] = red[0][tid] + red[1][tid] + red[2][tid] + red[3][tid];
    __syncthreads();

    // lq = low_q; lv = low_v = lowx_v + 2 * lq . C^T   (per row)
    float lq[ROWS][4], lv[ROWS][4];
    {
        float cm[16];
#pragma unroll
        for (int i = 0; i < 16; ++i) cm[i] = C[i];
#pragma unroll
        for (int m = 0; m < ROWS; ++m) {
#pragma unroll
            for (int r = 0; r < 4; ++r) lq[m][r] = lows[m * 4 + r];
#pragma unroll
            for (int rp = 0; rp < 4; ++rp) {
                float s = lows[8 + m * 4 + rp];
#pragma unroll
                for (int r = 0; r < 4; ++r) s += 2.f * lq[m][r] * cm[rp * 4 + r];
                lv[m][rp] = s;
            }
        }
    }

    // ---- Phase 2: out = 2*(x + lq.Bq[d] + lv.Bv[d])  (x from registers) ----
#pragma unroll
    for (int c = 0; c < CHUNKS; ++c) {
        const int d0 = c * (THREADS * 4) + tid * 4;
        float o[ROWS][4];
#pragma unroll
        for (int i = 0; i < 4; ++i) {
            float4 bq = *reinterpret_cast<const float4*>(B_q + (size_t)(d0 + i) * 4);
            float4 bv = *reinterpret_cast<const float4*>(B_v + (size_t)(d0 + i) * 4);
#pragma unroll
            for (int m = 0; m < ROWS; ++m) {
                float4 xv = xr[m][c];
                float xs = (i == 0) ? xv.x : (i == 1) ? xv.y : (i == 2) ? xv.z : xv.w;
                float dq = lq[m][0] * bq.x + lq[m][1] * bq.y + lq[m][2] * bq.z + lq[m][3] * bq.w;
                float dv = lv[m][0] * bv.x + lv[m][1] * bv.y + lv[m][2] * bv.z + lv[m][3] * bv.w;
                o[m][i] = 2.f * (xs + dq + dv);
            }
        }
#pragma unroll
        for (int m = 0; m < ROWS; ++m) {
            float4 ov = make_float4(o[m][0], o[m][1], o[m][2], o[m][3]);
            *reinterpret_cast<float4*>(out + (row0 + m) * H + d0) = ov;
        }
    }
}

extern "C" void kernel_launch(void* const* d_in, const int* in_sizes, int n_in,
                              void* d_out, int out_size, void* d_ws, size_t ws_size,
                              hipStream_t stream) {
    const float* x   = (const float*)d_in[0];
    const float* A_q = (const float*)d_in[1];
    const float* B_q = (const float*)d_in[2];
    const float* A_v = (const float*)d_in[3];
    const float* B_v = (const float*)d_in[4];
    float* out = (float*)d_out;
    float* C   = (float*)d_ws;          // 16 floats

    const int rows = in_sizes[0] / H;   // B*S = 8192

    compute_C_kernel<<<1, THREADS, 0, stream>>>(A_v, B_q, C);
    lora_fused_kernel<<<rows / ROWS, THREADS, 0, stream>>>(
        x, A_q, B_q, A_v, B_v, C, out);
}